// Round 1
// baseline (8723.108 us; speedup 1.0000x reference)
//
#include <hip/hip_runtime.h>

#define B_ 2
#define S_ 1024
#define E_ 1024
#define H_ 16
#define DK_ 64
#define F_ 4096
#define L_ 4
#define V_ 32000
#define BS_ (B_*S_)   // 2048

typedef short bf16x8 __attribute__((ext_vector_type(8)));
typedef float f32x4 __attribute__((ext_vector_type(4)));

__device__ inline unsigned short f2b(float x) {
  union { float f; unsigned u; } un; un.f = x;
  unsigned r = un.u + 0x7fffu + ((un.u >> 16) & 1u);
  return (unsigned short)(r >> 16);
}
__device__ inline float b2f(unsigned short b) {
  union { unsigned u; float f; } un; un.u = ((unsigned)b) << 16;
  return un.f;
}

// Detect whether float inputs are stored as bf16 (flag=1) or f32 (flag=0).
// mlp_norm_w is all-ones: f32 word = 0x3F800000, bf16 pair = 0x3F803F80.
__global__ void detect_kernel(const unsigned* __restrict__ normw, int* __restrict__ flag) {
  if (threadIdx.x == 0) *flag = (normw[0] == 0x3F800000u) ? 0 : 1;
}

__global__ __launch_bounds__(256) void embed_kernel(
    const int* __restrict__ tokens, const void* __restrict__ table,
    float* __restrict__ emb, const int* __restrict__ flagp)
{
  const int flag = *flagp;
  const int row = blockIdx.x;           // (b,s) 0..2047
  const int tok = tokens[row];
  const int tid = threadIdx.x;
  #pragma unroll
  for (int c = 0; c < 4; c++) {
    const int i = tid + 256 * c;
    float v;
    if (flag) v = b2f(((const unsigned short*)table)[(long)tok * E_ + i]);
    else      v = ((const float*)table)[(long)tok * E_ + i];
    emb[(long)row * E_ + i] = v;
  }
}

// C[M,N] = A[M,K] (f32, staged->bf16) x B[K,N] (bf16 or f32 weights)
// amode: 0 = A row-major [M,K]; 1 = A gathered from bhsd layout (K index = h*64+d)
// B element (kk,nn) at: bOff + (nn>>6)*bsH + kk*bsK + (nn&63)
// cmode: 0 = C[row*N+col] = v (+resid);  1 = scatter to bhsk: C[(((b*H+h)*S)+s)*64+dk]
//        2 = logits: v += bias[col]; store (bf16|f32 per flag) to outb
//        3 = C[idx] = resid[idx] * elu(v)   (fused up * elu(gate))
// blockIdx.z selects (Bw,C) among {(Bw,C),(Bw1,C1),(Bw2,C2)} for fused QKV.
// Tile: BM x BN, 256 threads = 4 waves as 2x2, each wave (BM/2)x(BN/2),
// fragments FM=BM/32 x FN=BN/32 of 16x16, K-step 32.
template<int BM, int BN>
__global__ __launch_bounds__(256) void gemm_kernel(
    const float* __restrict__ A, const void* __restrict__ Bw,
    const void* __restrict__ Bw1, const void* __restrict__ Bw2,
    float* __restrict__ C, float* __restrict__ C1, float* __restrict__ C2,
    const float* __restrict__ resid,
    const void* __restrict__ bias, void* __restrict__ outb,
    const int* __restrict__ flagp,
    int M, int N, int K, int amode, long bOff, long bsH, long bsK, int cmode)
{
  const int flag = *flagp;
  if (blockIdx.z == 1)      { Bw = Bw1; C = C1; }
  else if (blockIdx.z == 2) { Bw = Bw2; C = C2; }

  // pad to 40 ushorts (80B, multiple of 16B): frag reads conflict-free,
  // transpose writes <=4-way.
  __shared__ unsigned short As[BM][40];   // [m][k] bf16
  __shared__ unsigned short Bs[BN][40];   // [n][k] bf16 (transposed at staging)

  const int tid = threadIdx.x;
  const int m0 = blockIdx.y * BM, n0g = blockIdx.x * BN;

  constexpr int WM = BM / 2, WN = BN / 2;
  constexpr int FM = WM / 16, FN = WN / 16;
  constexpr int EA = BM / 8;              // f32 A-elems per thread per K-step
  constexpr int TPR = 32 / EA;            // threads per A row

  f32x4 acc[FM][FN] = {};

  const int arow = tid / TPR, ak0 = (tid % TPR) * EA;
  const int w = tid >> 6, lane = tid & 63;
  const int wr = w & 1, wc = w >> 1;
  const int lr = lane & 15, quad = lane >> 4;

  for (int k0 = 0; k0 < K; k0 += 32) {
    { // ---- stage A tile (BM x 32 f32 -> bf16) ----
      const int mm = m0 + arow;
      const int kk = k0 + ak0;
      long aoff;
      if (amode == 0) aoff = (long)mm * K + kk;
      else {
        const int bb = mm >> 10, ss = mm & 1023, hh = kk >> 6, dd = kk & 63;
        aoff = ((((long)bb * H_ + hh) * S_) + ss) * 64 + dd;
      }
      const float4* ap = (const float4*)(A + aoff);
      unsigned short* dst = &As[arow][ak0];
      #pragma unroll
      for (int g = 0; g < EA / 4; g++) {
        const float4 v = ap[g];
        dst[4*g+0] = f2b(v.x); dst[4*g+1] = f2b(v.y);
        dst[4*g+2] = f2b(v.z); dst[4*g+3] = f2b(v.w);
      }
    }
    { // ---- stage B tile (32 x BN), transpose into Bs[n][k] ----
      #pragma unroll
      for (int i = 0; i < BN / 64; i++) {
        const int kloc = tid & 31;
        const int nloc = ((tid >> 5) + i * 8) * 8;
        const int kk = k0 + kloc;
        const long nn = (long)n0g + nloc;
        const long boff = bOff + (nn >> 6) * bsH + (long)kk * bsK + (nn & 63);
        unsigned short bv[8];
        if (flag) {
          const uint4 raw = *(const uint4*)((const unsigned short*)Bw + boff);
          bv[0]=raw.x&0xffffu; bv[1]=raw.x>>16; bv[2]=raw.y&0xffffu; bv[3]=raw.y>>16;
          bv[4]=raw.z&0xffffu; bv[5]=raw.z>>16; bv[6]=raw.w&0xffffu; bv[7]=raw.w>>16;
        } else {
          const float4* bp = (const float4*)((const float*)Bw + boff);
          const float4 f0 = bp[0], f1 = bp[1];
          bv[0]=f2b(f0.x); bv[1]=f2b(f0.y); bv[2]=f2b(f0.z); bv[3]=f2b(f0.w);
          bv[4]=f2b(f1.x); bv[5]=f2b(f1.y); bv[6]=f2b(f1.z); bv[7]=f2b(f1.w);
        }
        #pragma unroll
        for (int j = 0; j < 8; j++) Bs[nloc + j][kloc] = bv[j];
      }
    }
    __syncthreads();
    bf16x8 af[FM], bg[FN];
    #pragma unroll
    for (int fm = 0; fm < FM; fm++)
      af[fm] = *(const bf16x8*)&As[wr * WM + fm * 16 + lr][quad * 8];
    #pragma unroll
    for (int fn = 0; fn < FN; fn++)
      bg[fn] = *(const bf16x8*)&Bs[wc * WN + fn * 16 + lr][quad * 8];
    #pragma unroll
    for (int fm = 0; fm < FM; fm++)
      #pragma unroll
      for (int fn = 0; fn < FN; fn++)
        acc[fm][fn] = __builtin_amdgcn_mfma_f32_16x16x32_bf16(af[fm], bg[fn], acc[fm][fn], 0, 0, 0);
    __syncthreads();
  }

  // epilogue: C/D layout col=lane&15, row=quad*4+reg  [HW-verified]
  #pragma unroll
  for (int fm = 0; fm < FM; fm++)
    #pragma unroll
    for (int fn = 0; fn < FN; fn++)
      #pragma unroll
      for (int r = 0; r < 4; r++) {
        const int row = m0 + wr * WM + fm * 16 + quad * 4 + r;
        const int col = n0g + wc * WN + fn * 16 + lr;
        float v = acc[fm][fn][r];
        if (cmode == 0) {
          const long idx = (long)row * N + col;
          if (resid) v += resid[idx];
          C[idx] = v;
        } else if (cmode == 1) {
          const int bb = row >> 10, ss = row & 1023, hh = col >> 6, dd = col & 63;
          C[((((long)bb * H_ + hh) * S_) + ss) * 64 + dd] = v;
        } else if (cmode == 2) {
          const float bvl = flag ? b2f(((const unsigned short*)bias)[col])
                                 : ((const float*)bias)[col];
          v += bvl;
          const long idx = (long)row * N + col;
          if (flag) ((unsigned short*)outb)[idx] = f2b(v);
          else      ((float*)outb)[idx] = v;
        } else {
          const long idx = (long)row * N + col;
          const float g = (v > 0.0f) ? v : expm1f(v);
          C[idx] = resid[idx] * g;
        }
      }
}

// In-place RoPE on q and k (bhsk layout). One wave per row of 64.
__global__ __launch_bounds__(64) void rope_kernel(float* __restrict__ q, float* __restrict__ k) {
  const int idx = blockIdx.x;                 // 0 .. 2*B*H*S-1
  float* buf = (idx < B_ * H_ * S_) ? q : k;
  const int r = (idx < B_ * H_ * S_) ? idx : idx - B_ * H_ * S_;
  const int s = r & (S_ - 1);
  const int i = threadIdx.x;                  // 0..63
  float* xr = buf + (long)r * 64;
  const float x  = xr[i];
  const float xs = xr[(i + 32) & 63];         // swapped half
  const int im = i & 31;
  const float theta = expf(-(float)im * 0.28782313662425575f);  // ln(10000)/32
  const float ang = (float)s * theta;
  const float sign = (i < 32) ? -1.0f : 1.0f;
  xr[i] = cosf(ang) * x + sign * sinf(ang) * xs;
}

// One block per (s, b*h): scores row in LDS, block softmax, PV.
__global__ __launch_bounds__(256) void attn_kernel(
    const float* __restrict__ q, const float* __restrict__ k,
    const float* __restrict__ v, float* __restrict__ o)
{
  const int s = blockIdx.x;
  const int bh = blockIdx.y;
  const int tid = threadIdx.x;
  const float* K = k + (long)bh * S_ * 64;
  const float* V = v + (long)bh * S_ * 64;
  __shared__ float qs[64];
  __shared__ float sc[S_];
  __shared__ float redm[4], reds[4], osum[4][64];
  if (tid < 64) qs[tid] = q[((long)bh * S_ + s) * 64 + tid];
  __syncthreads();
  float lmax = -__builtin_inff();
  for (int t = tid; t < S_; t += 256) {
    float d = -__builtin_inff();
    if (t <= s) {
      const float4* kr = (const float4*)(K + (long)t * 64);
      float a = 0.0f;
      #pragma unroll
      for (int j = 0; j < 16; j++) {
        const float4 kv = kr[j];
        a += kv.x * qs[4*j] + kv.y * qs[4*j+1] + kv.z * qs[4*j+2] + kv.w * qs[4*j+3];
      }
      d = a * 0.125f;                          // 1/sqrt(64)
    }
    sc[t] = d;
    lmax = fmaxf(lmax, d);
  }
  #pragma unroll
  for (int off = 32; off > 0; off >>= 1) lmax = fmaxf(lmax, __shfl_down(lmax, off, 64));
  if ((tid & 63) == 0) redm[tid >> 6] = lmax;
  __syncthreads();
  const float mx = fmaxf(fmaxf(redm[0], redm[1]), fmaxf(redm[2], redm[3]));
  float lsum = 0.0f;
  for (int t = tid; t < S_; t += 256) {
    const float e = expf(sc[t] - mx);          // exp(-inf)=0 handles mask
    sc[t] = e;
    lsum += e;
  }
  #pragma unroll
  for (int off = 32; off > 0; off >>= 1) lsum += __shfl_down(lsum, off, 64);
  if ((tid & 63) == 0) reds[tid >> 6] = lsum;
  __syncthreads();
  const float tot = reds[0] + reds[1] + reds[2] + reds[3];
  const int d = tid & 63, g = tid >> 6;
  const int tend = min(S_, s + 1);
  float accv = 0.0f;
  const int t1 = min((g + 1) * 256, tend);
  for (int t = g * 256; t < t1; t++) accv += sc[t] * V[(long)t * 64 + d];
  osum[g][d] = accv;
  __syncthreads();
  if (tid < 64) {
    const float r = (osum[0][tid] + osum[1][tid] + osum[2][tid] + osum[3][tid]) / tot;
    o[((long)bh * S_ + s) * 64 + tid] = r;
  }
}

__global__ __launch_bounds__(256) void rmsnorm_kernel(
    const float* __restrict__ x, const void* __restrict__ wsrc,
    float* __restrict__ y, const int* __restrict__ flagp, long wOff)
{
  const int flag = *flagp;
  const int row = blockIdx.x;
  const int tid = threadIdx.x;
  const float* xr = x + (long)row * E_;
  float ss = 0.0f;
  #pragma unroll
  for (int c = 0; c < 4; c++) { const float vv = xr[tid + 256 * c]; ss += vv * vv; }
  __shared__ float red[4];
  #pragma unroll
  for (int off = 32; off > 0; off >>= 1) ss += __shfl_down(ss, off, 64);
  if ((tid & 63) == 0) red[tid >> 6] = ss;
  __syncthreads();
  const float tot = red[0] + red[1] + red[2] + red[3];
  const float scale = rsqrtf(tot * (1.0f / E_) + 1.1920929e-7f);
  #pragma unroll
  for (int c = 0; c < 4; c++) {
    const int i = tid + 256 * c;
    const float wv = flag ? b2f(((const unsigned short*)wsrc)[wOff + i])
                          : ((const float*)wsrc)[wOff + i];
    y[(long)row * E_ + i] = xr[i] * scale * wv;
  }
}

extern "C" void kernel_launch(void* const* d_in, const int* in_sizes, int n_in,
                              void* d_out, int out_size, void* d_ws, size_t ws_size,
                              hipStream_t stream) {
  const int* tokens = (const int*)d_in[0];
  const void* table = d_in[1];
  const void* Wq = d_in[2];
  const void* Wk = d_in[3];
  const void* Wv = d_in[4];
  const void* Wproj = d_in[5];
  const void* normw = d_in[6];
  const void* Wup = d_in[7];
  const void* Wgate = d_in[8];
  const void* Wdown = d_in[9];
  const void* predW = d_in[10];
  const void* predb = d_in[11];

  int* flagp = (int*)d_ws;
  float* base = (float*)d_ws + 64;               // 256B offset for flag slot
  const long NE = (long)BS_ * E_;                // 2097152
  float* emb   = base;
  float* hnorm = emb + NE;
  float* qb    = hnorm + NE;
  float* kb    = qb + NE;
  float* vb    = kb + NE;
  float* ob    = vb + NE;
  float* up    = ob + NE;
  float* gate  = up + (long)BS_ * F_;            // +8388608

  detect_kernel<<<dim3(1), dim3(64), 0, stream>>>((const unsigned*)normw, flagp);
  embed_kernel<<<dim3(BS_), dim3(256), 0, stream>>>(tokens, table, emb, flagp);

  for (int l = 0; l < L_; l++) {
    const long offQKV = (long)l * H_ * E_ * DK_;   // 1048576
    const long offP   = (long)l * E_ * E_;
    const long offN   = (long)l * E_;
    const long offUG  = (long)l * E_ * F_;
    const long offD   = (long)l * F_ * E_;

    // q,k,v fused via gridDim.z: [2048,1024] x per-head [E,DK]
    gemm_kernel<128,128><<<dim3(8, 16, 3), dim3(256), 0, stream>>>(
        emb, Wq, Wk, Wv, qb, kb, vb, nullptr, nullptr, nullptr, flagp,
        BS_, H_ * DK_, E_, 0, offQKV, (long)E_ * DK_, 64, 1);

    rope_kernel<<<dim3(2 * B_ * H_ * S_), dim3(64), 0, stream>>>(qb, kb);
    attn_kernel<<<dim3(S_, B_ * H_), dim3(256), 0, stream>>>(qb, kb, vb, ob);

    // emb += o @ Wproj   (A gathered from bhsd); N=1024 -> 128x64 tile, 256 blocks
    gemm_kernel<128,64><<<dim3(16, 16, 1), dim3(256), 0, stream>>>(
        ob, Wproj, nullptr, nullptr, emb, nullptr, nullptr, emb, nullptr, nullptr, flagp,
        BS_, E_, E_, 1, offP, 64, E_, 0);

    rmsnorm_kernel<<<dim3(BS_), dim3(256), 0, stream>>>(emb, normw, hnorm, flagp, offN);

    // up = h @ Wup ; gate-buf = up * elu(h @ Wgate) ; emb += gate-buf @ Wdown
    gemm_kernel<128,128><<<dim3(32, 16, 1), dim3(256), 0, stream>>>(
        hnorm, Wup, nullptr, nullptr, up, nullptr, nullptr, nullptr, nullptr, nullptr, flagp,
        BS_, F_, E_, 0, offUG, 64, F_, 0);
    gemm_kernel<128,128><<<dim3(32, 16, 1), dim3(256), 0, stream>>>(
        hnorm, Wgate, nullptr, nullptr, gate, nullptr, nullptr, up, nullptr, nullptr, flagp,
        BS_, F_, E_, 0, offUG, 64, F_, 3);
    gemm_kernel<128,64><<<dim3(16, 16, 1), dim3(256), 0, stream>>>(
        gate, Wdown, nullptr, nullptr, emb, nullptr, nullptr, emb, nullptr, nullptr, flagp,
        BS_, E_, F_, 0, offD, 64, E_, 0);
  }

  // logits = emb @ pred_W + pred_b  -> d_out (dtype per flag)
  gemm_kernel<128,128><<<dim3(V_ / 128, BS_ / 128, 1), dim3(256), 0, stream>>>(
      emb, predW, nullptr, nullptr, nullptr, nullptr, nullptr, nullptr, predb, d_out, flagp,
      BS_, V_, E_, 0, 0, 64, V_, 2);
}

// Round 2
// 3366.337 us; speedup vs baseline: 2.5913x; 2.5913x over previous
//
#include <hip/hip_runtime.h>

#define B_ 2
#define S_ 1024
#define E_ 1024
#define H_ 16
#define DK_ 64
#define F_ 4096
#define L_ 4
#define V_ 32000
#define BS_ (B_*S_)   // 2048

typedef short bf16x8 __attribute__((ext_vector_type(8)));
typedef float f32x4 __attribute__((ext_vector_type(4)));

__device__ inline unsigned short f2b(float x) {
  union { float f; unsigned u; } un; un.f = x;
  unsigned r = un.u + 0x7fffu + ((un.u >> 16) & 1u);
  return (unsigned short)(r >> 16);
}
__device__ inline float b2f(unsigned short b) {
  union { unsigned u; float f; } un; un.u = ((unsigned)b) << 16;
  return un.f;
}

// Detect whether float inputs are stored as bf16 (flag=1) or f32 (flag=0).
// mlp_norm_w is all-ones: f32 word = 0x3F800000, bf16 pair = 0x3F803F80.
__global__ void detect_kernel(const unsigned* __restrict__ normw, int* __restrict__ flag) {
  if (threadIdx.x == 0) *flag = (normw[0] == 0x3F800000u) ? 0 : 1;
}

__global__ __launch_bounds__(256) void embed_kernel(
    const int* __restrict__ tokens, const void* __restrict__ table,
    float* __restrict__ emb, const int* __restrict__ flagp)
{
  const int flag = *flagp;
  const int row = blockIdx.x;           // (b,s) 0..2047
  const int tok = tokens[row];
  const int tid = threadIdx.x;
  #pragma unroll
  for (int c = 0; c < 4; c++) {
    const int i = tid + 256 * c;
    float v;
    if (flag) v = b2f(((const unsigned short*)table)[(long)tok * E_ + i]);
    else      v = ((const float*)table)[(long)tok * E_ + i];
    emb[(long)row * E_ + i] = v;
  }
}

// C[M,N] = A[M,K] (f32, staged->bf16) x B[K,N] (bf16 or f32 weights)
// amode: 0 = A row-major [M,K]; 1 = A gathered from bhsd layout (K index = h*64+d)
// B element (kk,nn) at: bOff + (nn>>6)*bsH + kk*bsK + (nn&63)
// cmode: 0 = C[row*N+col] = v (+resid);  1 = scatter to bhsk: C[(((b*H+h)*S)+s)*64+dk]
//        2 = logits: v += bias[col]; store (bf16|f32 per flag) to outb
//        3 = C[idx] = resid[idx] * elu(v)   (fused up * elu(gate))
// blockIdx.z selects (Bw,C) among {(Bw,C),(Bw1,C1),(Bw2,C2)} for fused QKV.
template<int BM, int BN>
__global__ __launch_bounds__(256) void gemm_kernel(
    const float* __restrict__ A, const void* __restrict__ Bw,
    const void* __restrict__ Bw1, const void* __restrict__ Bw2,
    float* __restrict__ C, float* __restrict__ C1, float* __restrict__ C2,
    const float* __restrict__ resid,
    const void* __restrict__ bias, void* __restrict__ outb,
    const int* __restrict__ flagp,
    int M, int N, int K, int amode, long bOff, long bsH, long bsK, int cmode)
{
  const int flag = *flagp;
  if (blockIdx.z == 1)      { Bw = Bw1; C = C1; }
  else if (blockIdx.z == 2) { Bw = Bw2; C = C2; }

  __shared__ unsigned short As[BM][40];   // [m][k] bf16
  __shared__ unsigned short Bs[BN][40];   // [n][k] bf16 (transposed at staging)

  const int tid = threadIdx.x;
  const int m0 = blockIdx.y * BM, n0g = blockIdx.x * BN;

  constexpr int WM = BM / 2, WN = BN / 2;
  constexpr int FM = WM / 16, FN = WN / 16;
  constexpr int EA = BM / 8;              // f32 A-elems per thread per K-step
  constexpr int TPR = 32 / EA;            // threads per A row

  f32x4 acc[FM][FN] = {};

  const int arow = tid / TPR, ak0 = (tid % TPR) * EA;
  const int w = tid >> 6, lane = tid & 63;
  const int wr = w & 1, wc = w >> 1;
  const int lr = lane & 15, quad = lane >> 4;

  for (int k0 = 0; k0 < K; k0 += 32) {
    { // ---- stage A tile (BM x 32 f32 -> bf16) ----
      const int mm = m0 + arow;
      const int kk = k0 + ak0;
      long aoff;
      if (amode == 0) aoff = (long)mm * K + kk;
      else {
        const int bb = mm >> 10, ss = mm & 1023, hh = kk >> 6, dd = kk & 63;
        aoff = ((((long)bb * H_ + hh) * S_) + ss) * 64 + dd;
      }
      const float4* ap = (const float4*)(A + aoff);
      unsigned short* dst = &As[arow][ak0];
      #pragma unroll
      for (int g = 0; g < EA / 4; g++) {
        const float4 v = ap[g];
        dst[4*g+0] = f2b(v.x); dst[4*g+1] = f2b(v.y);
        dst[4*g+2] = f2b(v.z); dst[4*g+3] = f2b(v.w);
      }
    }
    { // ---- stage B tile (32 x BN), transpose into Bs[n][k] ----
      #pragma unroll
      for (int i = 0; i < BN / 64; i++) {
        const int kloc = tid & 31;
        const int nloc = ((tid >> 5) + i * 8) * 8;
        const int kk = k0 + kloc;
        const long nn = (long)n0g + nloc;
        const long boff = bOff + (nn >> 6) * bsH + (long)kk * bsK + (nn & 63);
        unsigned short bv[8];
        if (flag) {
          const uint4 raw = *(const uint4*)((const unsigned short*)Bw + boff);
          bv[0]=raw.x&0xffffu; bv[1]=raw.x>>16; bv[2]=raw.y&0xffffu; bv[3]=raw.y>>16;
          bv[4]=raw.z&0xffffu; bv[5]=raw.z>>16; bv[6]=raw.w&0xffffu; bv[7]=raw.w>>16;
        } else {
          const float4* bp = (const float4*)((const float*)Bw + boff);
          const float4 f0 = bp[0], f1 = bp[1];
          bv[0]=f2b(f0.x); bv[1]=f2b(f0.y); bv[2]=f2b(f0.z); bv[3]=f2b(f0.w);
          bv[4]=f2b(f1.x); bv[5]=f2b(f1.y); bv[6]=f2b(f1.z); bv[7]=f2b(f1.w);
        }
        #pragma unroll
        for (int j = 0; j < 8; j++) Bs[nloc + j][kloc] = bv[j];
      }
    }
    __syncthreads();
    bf16x8 af[FM], bg[FN];
    #pragma unroll
    for (int fm = 0; fm < FM; fm++)
      af[fm] = *(const bf16x8*)&As[wr * WM + fm * 16 + lr][quad * 8];
    #pragma unroll
    for (int fn = 0; fn < FN; fn++)
      bg[fn] = *(const bf16x8*)&Bs[wc * WN + fn * 16 + lr][quad * 8];
    #pragma unroll
    for (int fm = 0; fm < FM; fm++)
      #pragma unroll
      for (int fn = 0; fn < FN; fn++)
        acc[fm][fn] = __builtin_amdgcn_mfma_f32_16x16x32_bf16(af[fm], bg[fn], acc[fm][fn], 0, 0, 0);
    __syncthreads();
  }

  // epilogue: C/D layout col=lane&15, row=quad*4+reg  [HW-verified]
  #pragma unroll
  for (int fm = 0; fm < FM; fm++)
    #pragma unroll
    for (int fn = 0; fn < FN; fn++)
      #pragma unroll
      for (int r = 0; r < 4; r++) {
        const int row = m0 + wr * WM + fm * 16 + quad * 4 + r;
        const int col = n0g + wc * WN + fn * 16 + lr;
        float v = acc[fm][fn][r];
        if (cmode == 0) {
          const long idx = (long)row * N + col;
          if (resid) v += resid[idx];
          C[idx] = v;
        } else if (cmode == 1) {
          const int bb = row >> 10, ss = row & 1023, hh = col >> 6, dd = col & 63;
          C[((((long)bb * H_ + hh) * S_) + ss) * 64 + dd] = v;
        } else if (cmode == 2) {
          const float bvl = flag ? b2f(((const unsigned short*)bias)[col])
                                 : ((const float*)bias)[col];
          v += bvl;
          const long idx = (long)row * N + col;
          if (flag) ((unsigned short*)outb)[idx] = f2b(v);
          else      ((float*)outb)[idx] = v;
        } else {
          const long idx = (long)row * N + col;
          const float g = (v > 0.0f) ? v : expm1f(v);
          C[idx] = resid[idx] * g;
        }
      }
}

// In-place RoPE on q and k (bhsk layout). One wave per row of 64.
__global__ __launch_bounds__(64) void rope_kernel(float* __restrict__ q, float* __restrict__ k) {
  const int idx = blockIdx.x;                 // 0 .. 2*B*H*S-1
  float* buf = (idx < B_ * H_ * S_) ? q : k;
  const int r = (idx < B_ * H_ * S_) ? idx : idx - B_ * H_ * S_;
  const int s = r & (S_ - 1);
  const int i = threadIdx.x;                  // 0..63
  float* xr = buf + (long)r * 64;
  const float x  = xr[i];
  const float xs = xr[(i + 32) & 63];         // swapped half
  const int im = i & 31;
  const float theta = expf(-(float)im * 0.28782313662425575f);  // ln(10000)/32
  const float ang = (float)s * theta;
  const float sign = (i < 32) ? -1.0f : 1.0f;
  xr[i] = cosf(ang) * x + sign * sinf(ang) * xs;
}

// Flash-style MFMA attention. One block per (q-tile of 64, bh).
// 4 waves; wave w owns q-rows [w*16, w*16+16). Per K/V tile of 64:
// QK^T and PV via mfma_f32_16x16x32_bf16, online softmax in C-layout
// (row = quad*4+r; row-reduce = shfl_xor over the 16 lanes of the quad).
__global__ __launch_bounds__(256) void attn_kernel(
    const float* __restrict__ q, const float* __restrict__ k,
    const float* __restrict__ v, float* __restrict__ o)
{
  const int qt = blockIdx.x;        // 0..15
  const int bh = blockIdx.y;        // 0..31
  const int tid = threadIdx.x;
  const int w = tid >> 6, lane = tid & 63;
  const int lr = lane & 15, quad = lane >> 4;

  __shared__ unsigned short Qs[64][72];   // [s][dk]
  __shared__ unsigned short Ks[64][72];   // [t][dk]
  __shared__ unsigned short Vs[64][72];   // [d][t]  (transposed)
  __shared__ unsigned short Ps[64][72];   // [s][t]

  const float* Qg = q + ((long)bh * S_ + (long)qt * 64) * 64;
  const float* Kg = k + (long)bh * S_ * 64;
  const float* Vg = v + (long)bh * S_ * 64;

  { // stage Q tile (64x64 f32 -> bf16): row = tid>>2, cols (tid&3)*16..+15
    const int r = tid >> 2, c0 = (tid & 3) * 16;
    const float4* qp = (const float4*)(Qg + (long)r * 64 + c0);
    unsigned short* dst = &Qs[r][c0];
    #pragma unroll
    for (int g = 0; g < 4; g++) {
      const float4 vv = qp[g];
      dst[4*g+0]=f2b(vv.x); dst[4*g+1]=f2b(vv.y); dst[4*g+2]=f2b(vv.z); dst[4*g+3]=f2b(vv.w);
    }
  }
  __syncthreads();
  bf16x8 aq[2];
  aq[0] = *(const bf16x8*)&Qs[w*16 + lr][quad*8];
  aq[1] = *(const bf16x8*)&Qs[w*16 + lr][32 + quad*8];

  float mrow[4], lrow[4];
  #pragma unroll
  for (int r = 0; r < 4; r++) { mrow[r] = -__builtin_inff(); lrow[r] = 0.0f; }
  f32x4 oacc[4] = {};

  for (int kt = 0; kt <= qt; kt++) {
    { // stage K tile [t][dk] and V^T tile [d][t]
      const int r = tid >> 2, c0 = (tid & 3) * 16;
      const float4* kp = (const float4*)(Kg + (long)(kt*64 + r) * 64 + c0);
      unsigned short* dst = &Ks[r][c0];
      #pragma unroll
      for (int g = 0; g < 4; g++) {
        const float4 vv = kp[g];
        dst[4*g+0]=f2b(vv.x); dst[4*g+1]=f2b(vv.y); dst[4*g+2]=f2b(vv.z); dst[4*g+3]=f2b(vv.w);
      }
      const float4* vp = (const float4*)(Vg + (long)(kt*64 + r) * 64 + c0);
      #pragma unroll
      for (int g = 0; g < 4; g++) {
        const float4 vv = vp[g];
        Vs[c0+4*g+0][r]=f2b(vv.x); Vs[c0+4*g+1][r]=f2b(vv.y);
        Vs[c0+4*g+2][r]=f2b(vv.z); Vs[c0+4*g+3][r]=f2b(vv.w);
      }
    }
    __syncthreads();

    // QK^T: 4 t-fragments of 16
    f32x4 sfr[4];
    #pragma unroll
    for (int f = 0; f < 4; f++) {
      f32x4 accs = {};
      const bf16x8 bk0 = *(const bf16x8*)&Ks[f*16 + lr][quad*8];
      const bf16x8 bk1 = *(const bf16x8*)&Ks[f*16 + lr][32 + quad*8];
      accs = __builtin_amdgcn_mfma_f32_16x16x32_bf16(aq[0], bk0, accs, 0, 0, 0);
      accs = __builtin_amdgcn_mfma_f32_16x16x32_bf16(aq[1], bk1, accs, 0, 0, 0);
      sfr[f] = accs;
    }

    // scale + causal mask (only bites when kt == qt)
    const int sbase = qt*64 + w*16 + quad*4;
    #pragma unroll
    for (int f = 0; f < 4; f++) {
      const int t = kt*64 + f*16 + lr;
      #pragma unroll
      for (int r = 0; r < 4; r++) {
        float x = sfr[f][r] * 0.125f;
        if (t > sbase + r) x = -__builtin_inff();
        sfr[f][r] = x;
      }
    }

    // online softmax update per row r
    #pragma unroll
    for (int r = 0; r < 4; r++) {
      float mx = fmaxf(fmaxf(sfr[0][r], sfr[1][r]), fmaxf(sfr[2][r], sfr[3][r]));
      #pragma unroll
      for (int off = 8; off > 0; off >>= 1) mx = fmaxf(mx, __shfl_xor(mx, off, 64));
      const float mnew = fmaxf(mrow[r], mx);
      const float sc = expf(mrow[r] - mnew);   // 0 when mrow was -inf
      mrow[r] = mnew;
      lrow[r] *= sc;
      #pragma unroll
      for (int f = 0; f < 4; f++) oacc[f][r] *= sc;
      float rs = 0.0f;
      #pragma unroll
      for (int f = 0; f < 4; f++) {
        const float p = expf(sfr[f][r] - mnew);  // exp(-inf)=0 handles mask
        sfr[f][r] = p;
        rs += p;
      }
      #pragma unroll
      for (int off = 8; off > 0; off >>= 1) rs += __shfl_xor(rs, off, 64);
      lrow[r] += rs;
    }

    // P -> LDS (bf16) to reshape C-layout into A-fragment layout
    #pragma unroll
    for (int f = 0; f < 4; f++)
      #pragma unroll
      for (int r = 0; r < 4; r++)
        Ps[w*16 + quad*4 + r][f*16 + lr] = f2b(sfr[f][r]);
    __syncthreads();

    // PV: A = P[16s x 64t], B = V^T[d][t]
    const bf16x8 ap0 = *(const bf16x8*)&Ps[w*16 + lr][quad*8];
    const bf16x8 ap1 = *(const bf16x8*)&Ps[w*16 + lr][32 + quad*8];
    #pragma unroll
    for (int f = 0; f < 4; f++) {
      const bf16x8 bv0 = *(const bf16x8*)&Vs[f*16 + lr][quad*8];
      const bf16x8 bv1 = *(const bf16x8*)&Vs[f*16 + lr][32 + quad*8];
      oacc[f] = __builtin_amdgcn_mfma_f32_16x16x32_bf16(ap0, bv0, oacc[f], 0, 0, 0);
      oacc[f] = __builtin_amdgcn_mfma_f32_16x16x32_bf16(ap1, bv1, oacc[f], 0, 0, 0);
    }
    __syncthreads();   // protect Ks/Vs/Ps before next-tile staging
  }

  // write O = oacc / l, bhsd layout
  #pragma unroll
  for (int f = 0; f < 4; f++)
    #pragma unroll
    for (int r = 0; r < 4; r++) {
      const int s = qt*64 + w*16 + quad*4 + r;
      const int d = f*16 + lr;
      o[((long)bh * S_ + s) * 64 + d] = oacc[f][r] / lrow[r];
    }
}

__global__ __launch_bounds__(256) void rmsnorm_kernel(
    const float* __restrict__ x, const void* __restrict__ wsrc,
    float* __restrict__ y, const int* __restrict__ flagp, long wOff)
{
  const int flag = *flagp;
  const int row = blockIdx.x;
  const int tid = threadIdx.x;
  const float* xr = x + (long)row * E_;
  float ss = 0.0f;
  #pragma unroll
  for (int c = 0; c < 4; c++) { const float vv = xr[tid + 256 * c]; ss += vv * vv; }
  __shared__ float red[4];
  #pragma unroll
  for (int off = 32; off > 0; off >>= 1) ss += __shfl_down(ss, off, 64);
  if ((tid & 63) == 0) red[tid >> 6] = ss;
  __syncthreads();
  const float tot = red[0] + red[1] + red[2] + red[3];
  const float scale = rsqrtf(tot * (1.0f / E_) + 1.1920929e-7f);
  #pragma unroll
  for (int c = 0; c < 4; c++) {
    const int i = tid + 256 * c;
    const float wv = flag ? b2f(((const unsigned short*)wsrc)[wOff + i])
                          : ((const float*)wsrc)[wOff + i];
    y[(long)row * E_ + i] = xr[i] * scale * wv;
  }
}

extern "C" void kernel_launch(void* const* d_in, const int* in_sizes, int n_in,
                              void* d_out, int out_size, void* d_ws, size_t ws_size,
                              hipStream_t stream) {
  const int* tokens = (const int*)d_in[0];
  const void* table = d_in[1];
  const void* Wq = d_in[2];
  const void* Wk = d_in[3];
  const void* Wv = d_in[4];
  const void* Wproj = d_in[5];
  const void* normw = d_in[6];
  const void* Wup = d_in[7];
  const void* Wgate = d_in[8];
  const void* Wdown = d_in[9];
  const void* predW = d_in[10];
  const void* predb = d_in[11];

  int* flagp = (int*)d_ws;
  float* base = (float*)d_ws + 64;               // 256B offset for flag slot
  const long NE = (long)BS_ * E_;                // 2097152
  float* emb   = base;
  float* hnorm = emb + NE;
  float* qb    = hnorm + NE;
  float* kb    = qb + NE;
  float* vb    = kb + NE;
  float* ob    = vb + NE;
  float* up    = ob + NE;
  float* gate  = up + (long)BS_ * F_;            // +8388608

  detect_kernel<<<dim3(1), dim3(64), 0, stream>>>((const unsigned*)normw, flagp);
  embed_kernel<<<dim3(BS_), dim3(256), 0, stream>>>(tokens, table, emb, flagp);

  for (int l = 0; l < L_; l++) {
    const long offQKV = (long)l * H_ * E_ * DK_;   // 1048576
    const long offP   = (long)l * E_ * E_;
    const long offN   = (long)l * E_;
    const long offUG  = (long)l * E_ * F_;
    const long offD   = (long)l * F_ * E_;

    // q,k,v fused via gridDim.z: [2048,1024] x per-head [E,DK]
    gemm_kernel<128,128><<<dim3(8, 16, 3), dim3(256), 0, stream>>>(
        emb, Wq, Wk, Wv, qb, kb, vb, nullptr, nullptr, nullptr, flagp,
        BS_, H_ * DK_, E_, 0, offQKV, (long)E_ * DK_, 64, 1);

    rope_kernel<<<dim3(2 * B_ * H_ * S_), dim3(64), 0, stream>>>(qb, kb);
    attn_kernel<<<dim3(S_ / 64, B_ * H_), dim3(256), 0, stream>>>(qb, kb, vb, ob);

    // emb += o @ Wproj   (A gathered from bhsd); N=1024 -> 128x64 tile, 256 blocks
    gemm_kernel<128,64><<<dim3(16, 16, 1), dim3(256), 0, stream>>>(
        ob, Wproj, nullptr, nullptr, emb, nullptr, nullptr, emb, nullptr, nullptr, flagp,
        BS_, E_, E_, 1, offP, 64, E_, 0);

    rmsnorm_kernel<<<dim3(BS_), dim3(256), 0, stream>>>(emb, normw, hnorm, flagp, offN);

    // up = h @ Wup ; gate-buf = up * elu(h @ Wgate) ; emb += gate-buf @ Wdown
    gemm_kernel<128,128><<<dim3(32, 16, 1), dim3(256), 0, stream>>>(
        hnorm, Wup, nullptr, nullptr, up, nullptr, nullptr, nullptr, nullptr, nullptr, flagp,
        BS_, F_, E_, 0, offUG, 64, F_, 0);
    gemm_kernel<128,128><<<dim3(32, 16, 1), dim3(256), 0, stream>>>(
        hnorm, Wgate, nullptr, nullptr, gate, nullptr, nullptr, up, nullptr, nullptr, flagp,
        BS_, F_, E_, 0, offUG, 64, F_, 3);
    gemm_kernel<128,64><<<dim3(16, 16, 1), dim3(256), 0, stream>>>(
        gate, Wdown, nullptr, nullptr, emb, nullptr, nullptr, emb, nullptr, nullptr, flagp,
        BS_, E_, F_, 0, offD, 64, E_, 0);
  }

  // logits = emb @ pred_W + pred_b  -> d_out (dtype per flag)
  gemm_kernel<128,128><<<dim3(V_ / 128, BS_ / 128, 1), dim3(256), 0, stream>>>(
      emb, predW, nullptr, nullptr, nullptr, nullptr, nullptr, nullptr, predb, d_out, flagp,
      BS_, V_, E_, 0, 0, 64, V_, 2);
}